// Round 1
// baseline (381.541 us; speedup 1.0000x reference)
//
#include <hip/hip_runtime.h>

#define TPB 512

// Neural-CA update step, f32 baseline.
// One block per batch image (32x32, 16 ch). 512 threads, 2 pixels/thread.
// LDS: padded state tile [16][34][34] + padded new-alpha tile [34][34].
__global__ __launch_bounds__(TPB) void nca_kernel(
    const float* __restrict__ state,   // [B,16,32,32]
    const int*   __restrict__ rmask,   // [B,1,32,32]
    const float* __restrict__ w1,      // [128,48]
    const float* __restrict__ b1,      // [128]
    const float* __restrict__ w2,      // [16,128]
    const float* __restrict__ b2,      // [16]
    float* __restrict__ out)           // [B,16,32,32]
{
    __shared__ float sS[16 * 34 * 34];  // padded state, stride 34, zero halo
    __shared__ float sA[34 * 34];       // padded new alpha

    const int b   = blockIdx.x;
    const int tid = threadIdx.x;
    const float* gs = state + (size_t)b * 16 * 1024;

    // ---- zero the halos (state: 132 halo elems/ch; alpha: whole tile) ----
    for (int t = tid; t < 16 * 132 + 1156; t += TPB) {
        if (t < 16 * 132) {
            int c = t / 132, r = t % 132;
            int off;
            if (r < 34)        off = r;                       // row 0
            else if (r < 68)   off = 33 * 34 + (r - 34);      // row 33
            else if (r < 100)  off = (r - 68 + 1) * 34;       // col 0
            else               off = (r - 100 + 1) * 34 + 33; // col 33
            sS[c * 1156 + off] = 0.f;
        } else {
            sA[t - 16 * 132] = 0.f;
        }
    }

    // ---- stage state into padded LDS: 4096 float4 slots, 8 per thread ----
    #pragma unroll
    for (int k = 0; k < 8; ++k) {
        int q = tid + k * TPB;                     // 0..4095
        float4 v = reinterpret_cast<const float4*>(gs)[q];
        int c = q >> 8;                            // q / 256
        int rem = q & 255;
        int h = rem >> 3, w4 = rem & 7;
        float* dst = &sS[c * 1156 + (h + 1) * 34 + (w4 * 4 + 1)];
        dst[0] = v.x; dst[1] = v.y; dst[2] = v.z; dst[3] = v.w;
    }
    __syncthreads();

    float nx[2][16];
    float pooled_pre[2];

    #pragma unroll
    for (int i = 0; i < 2; ++i) {
        const int p = i * TPB + tid;               // 0..1023 flat pixel
        const int h = p >> 5, w = p & 31;
        const int base = (h + 1) * 34 + (w + 1);

        // ---- perception: [sobelX(16), sobelY(16), identity(16)] ----
        float per[48];
        #pragma unroll
        for (int c = 0; c < 16; ++c) {
            const float* s = &sS[c * 1156 + base];
            float m00 = s[-35], m01 = s[-34], m02 = s[-33];
            float m10 = s[-1],  m11 = s[0],   m12 = s[1];
            float m20 = s[33],  m21 = s[34],  m22 = s[35];
            per[c]      = (m02 + 2.f * m12 + m22) - (m00 + 2.f * m10 + m20);
            per[16 + c] = (m20 + 2.f * m21 + m22) - (m00 + 2.f * m01 + m02);
            per[32 + c] = m11;
            if (c == 3) {
                pooled_pre[i] = fmaxf(fmaxf(fmaxf(fmaxf(m00, m01), fmaxf(m02, m10)),
                                            fmaxf(fmaxf(m11, m12), fmaxf(m20, m21))),
                                      m22);
            }
        }

        // ---- MLP: h = relu(W1 p + b1); dx = W2 h + b2 (weights via s_load) ----
        float acc2[16];
        #pragma unroll
        for (int o = 0; o < 16; ++o) acc2[o] = 0.f;

        for (int j = 0; j < 128; ++j) {
            float a = b1[j];
            #pragma unroll
            for (int c = 0; c < 48; ++c) a = fmaf(w1[j * 48 + c], per[c], a);
            float hj = fmaxf(a, 0.f);
            #pragma unroll
            for (int o = 0; o < 16; ++o) acc2[o] = fmaf(w2[o * 128 + j], hj, acc2[o]);
        }

        const float mf = (float)rmask[b * 1024 + p];
        #pragma unroll
        for (int o = 0; o < 16; ++o)
            nx[i][o] = per[32 + o] + (acc2[o] + b2[o]) * mf;

        sA[base] = nx[i][3];                       // new alpha for post-pool
    }
    __syncthreads();

    // ---- alive gating + clip + store ----
    #pragma unroll
    for (int i = 0; i < 2; ++i) {
        const int p = i * TPB + tid;
        const int h = p >> 5, w = p & 31;
        const int base = (h + 1) * 34 + (w + 1);
        float a00 = sA[base - 35], a01 = sA[base - 34], a02 = sA[base - 33];
        float a10 = sA[base - 1],  a11 = sA[base],      a12 = sA[base + 1];
        float a20 = sA[base + 33], a21 = sA[base + 34], a22 = sA[base + 35];
        float mx = fmaxf(fmaxf(fmaxf(fmaxf(a00, a01), fmaxf(a02, a10)),
                               fmaxf(fmaxf(a11, a12), fmaxf(a20, a21))),
                         a22);
        bool alive = (pooled_pre[i] > 0.1f) && (mx > 0.1f);
        float* go = out + (size_t)b * 16384 + p;
        #pragma unroll
        for (int o = 0; o < 16; ++o) {
            float v = alive ? fminf(fmaxf(nx[i][o], 0.f), 1.f) : 0.f;
            go[o * 1024] = v;
        }
    }
}

extern "C" void kernel_launch(void* const* d_in, const int* in_sizes, int n_in,
                              void* d_out, int out_size, void* d_ws, size_t ws_size,
                              hipStream_t stream) {
    const float* state = (const float*)d_in[0];
    const int*   rmask = (const int*)d_in[1];
    const float* w1    = (const float*)d_in[2];
    const float* b1    = (const float*)d_in[3];
    const float* w2    = (const float*)d_in[4];
    const float* b2    = (const float*)d_in[5];
    float* outp = (float*)d_out;

    const int B = in_sizes[0] / (16 * 32 * 32);   // 1024
    hipLaunchKernelGGL(nca_kernel, dim3(B), dim3(TPB), 0, stream,
                       state, rmask, w1, b1, w2, b2, outp);
}

// Round 4
// 187.843 us; speedup vs baseline: 2.0312x; 2.0312x over previous
//
#include <hip/hip_runtime.h>
#include <hip/hip_bf16.h>

#define TPB 256

typedef __attribute__((ext_vector_type(8))) short short8v;   // 8 bf16 (4 VGPRs) MFMA operand
typedef __attribute__((ext_vector_type(4))) float f32x4;     // MFMA accumulator

__device__ __forceinline__ unsigned short f2bf(float f) {
    union { __hip_bfloat16 b; unsigned short u; } cv;
    cv.b = __float2bfloat16(f);   // round-to-nearest
    return cv.u;
}
__device__ __forceinline__ float bf2f(unsigned int u) {
    return __uint_as_float(u << 16);
}
__device__ __forceinline__ unsigned int packbf(float x, float y) {
    return (unsigned int)f2bf(x) | ((unsigned int)f2bf(y) << 16);
}

// One block per image. 4 waves. 16 strips of 64 px (2 image rows each).
// GEMM1: H[64x128] = relu(P[64x48pad64] * W1^T) via mfma_f32_16x16x32_bf16
// GEMM2: DX[64x16] = H * W2^T. W1/W2 fragments live in registers.
__global__ __launch_bounds__(TPB, 2) void nca_mfma(
    const float* __restrict__ state,   // [B,16,32,32]
    const int*   __restrict__ rmask,   // [B,1,32,32]
    const float* __restrict__ w1,      // [128,48]
    const float* __restrict__ b1,      // [128]
    const float* __restrict__ w2,      // [16,128]
    const float* __restrict__ b2,      // [16]
    float* __restrict__ out)           // [B,16,32,32]
{
    // LDS: 39168 + 9216 + 17408 + 4624 + 1024 = 71440 B  -> 2 blocks/CU
    __shared__ __align__(16) unsigned short sSt[16 * 34 * 36]; // bf16 state, row stride 36, data at [h+1][w+2]
    __shared__ __align__(16) unsigned short sP [64 * 72];      // perception, row stride 72 (144B), K 0..47 (+pad to 64)
    __shared__ __align__(16) unsigned short sH [64 * 136];     // hidden bf16, row stride 136 (272B)
    __shared__ __align__(16) float          sA [34 * 34];      // new alpha, padded, f32
    __shared__ unsigned char                sPre[1024];        // pre-state alive pool

    const int b    = blockIdx.x;
    const int tid  = threadIdx.x;
    const int lane = tid & 63;
    const int wv   = tid >> 6;     // wave 0..3
    const int lr   = lane & 15;
    const int lg   = lane >> 4;    // 0..3

    // ---------------- weight fragments (registers) ----------------
    // GEMM1 B-frag, ntile n: B_n[k][j] = W1[j*8+n][k]  (feature-interleaved)
    // lane holds col j=lr, k = kk*32 + lg*8 + e. K padded 48->64 with zeros.
    short8v w1f[8][2];
    short8v w2f[4];
    float   b1v[8];
    #pragma unroll
    for (int n = 0; n < 8; ++n) {
        const int f = lr * 8 + n;
        #pragma unroll
        for (int kk = 0; kk < 2; ++kk) {
            const int k0 = kk * 32 + lg * 8;
            short8v v;
            if (k0 < 48) {
                const float4 x0 = *reinterpret_cast<const float4*>(w1 + f * 48 + k0);
                const float4 x1 = *reinterpret_cast<const float4*>(w1 + f * 48 + k0 + 4);
                v[0]=(short)f2bf(x0.x); v[1]=(short)f2bf(x0.y); v[2]=(short)f2bf(x0.z); v[3]=(short)f2bf(x0.w);
                v[4]=(short)f2bf(x1.x); v[5]=(short)f2bf(x1.y); v[6]=(short)f2bf(x1.z); v[7]=(short)f2bf(x1.w);
            } else {
                #pragma unroll
                for (int e = 0; e < 8; ++e) v[e] = 0;
            }
            w1f[n][kk] = v;
        }
        b1v[n] = b1[f];
    }
    // GEMM2 B-frag: B[k][j] = W2[j][k]; lane: j=lr, k = ks*32 + lg*8 + e (K=128 exact)
    #pragma unroll
    for (int ks = 0; ks < 4; ++ks) {
        const int k0 = ks * 32 + lg * 8;
        const float4 x0 = *reinterpret_cast<const float4*>(w2 + lr * 128 + k0);
        const float4 x1 = *reinterpret_cast<const float4*>(w2 + lr * 128 + k0 + 4);
        short8v v;
        v[0]=(short)f2bf(x0.x); v[1]=(short)f2bf(x0.y); v[2]=(short)f2bf(x0.z); v[3]=(short)f2bf(x0.w);
        v[4]=(short)f2bf(x1.x); v[5]=(short)f2bf(x1.y); v[6]=(short)f2bf(x1.z); v[7]=(short)f2bf(x1.w);
        w2f[ks] = v;
    }
    const float b2v = b2[lr];

    // ---------------- zero LDS (halos + K-pad must be 0) ----------------
    for (int i = tid; i < 16*34*36/2; i += TPB) reinterpret_cast<unsigned int*>(sSt)[i] = 0u;
    for (int i = tid; i < 64*72/2;    i += TPB) reinterpret_cast<unsigned int*>(sP)[i]  = 0u;
    for (int i = tid; i < 34*34;      i += TPB) sA[i] = 0.f;
    __syncthreads();

    // ---------------- stage state -> bf16 LDS (coalesced float4) ----------------
    const float* gs = state + (size_t)b * 16384;
    #pragma unroll
    for (int k = 0; k < 16; ++k) {
        const int q = tid + k * TPB;                 // 0..4095 float4s
        const float4 v = reinterpret_cast<const float4*>(gs)[q];
        const int c = q >> 8, rem = q & 255;
        const int h = rem >> 3, wg = rem & 7;
        const int eo = c * 1224 + (h + 1) * 36 + (wg * 4 + 2);
        reinterpret_cast<unsigned int*>(&sSt[eo])[0] = packbf(v.x, v.y);
        reinterpret_cast<unsigned int*>(&sSt[eo])[1] = packbf(v.z, v.w);
    }
    __syncthreads();

    // ---------------- pre-state alive pool ----------------
    for (int p = tid; p < 1024; p += TPB) {
        const int h = p >> 5, w = p & 31;
        const unsigned short* sa = &sSt[3 * 1224 + h * 36 + (w + 1)];
        float m =          bf2f(sa[0]);
        m = fmaxf(m, bf2f(sa[1]));  m = fmaxf(m, bf2f(sa[2]));
        m = fmaxf(m, bf2f(sa[36])); m = fmaxf(m, bf2f(sa[37])); m = fmaxf(m, bf2f(sa[38]));
        m = fmaxf(m, bf2f(sa[72])); m = fmaxf(m, bf2f(sa[73])); m = fmaxf(m, bf2f(sa[74]));
        sPre[p] = (m > 0.1f) ? 1 : 0;
    }

    // gating helper: gate 64 px of a previous strip; this wave's 16 px held in xp[4]
    auto do_gate = [&](int pb, const float* xp) {
        float av = 0.f;
        if (lane < 16) {
            const int p = pb + lane;
            const int h = p >> 5, w = p & 31;
            const float* sa = &sA[h * 34 + w];
            float m =          sa[0];
            m = fmaxf(m, sa[1]);  m = fmaxf(m, sa[2]);
            m = fmaxf(m, sa[34]); m = fmaxf(m, sa[35]); m = fmaxf(m, sa[36]);
            m = fmaxf(m, sa[68]); m = fmaxf(m, sa[69]); m = fmaxf(m, sa[70]);
            av = ((m > 0.1f) && (sPre[p] != 0)) ? 1.f : 0.f;
        }
        const float g0 = __shfl(av, lg * 4 + 0);
        const float g1 = __shfl(av, lg * 4 + 1);
        const float g2 = __shfl(av, lg * 4 + 2);
        const float g3 = __shfl(av, lg * 4 + 3);
        float4 ov;
        ov.x = g0 * fminf(fmaxf(xp[0], 0.f), 1.f);
        ov.y = g1 * fminf(fmaxf(xp[1], 0.f), 1.f);
        ov.z = g2 * fminf(fmaxf(xp[2], 0.f), 1.f);
        ov.w = g3 * fminf(fmaxf(xp[3], 0.f), 1.f);
        *reinterpret_cast<float4*>(&out[(size_t)b * 16384 + lr * 1024 + pb + lg * 4]) = ov;
    };

    float xp[4];
    int pbase_prev = 0;

    for (int s = 0; s < 16; ++s) {
        // ===== [A] perception: 2 px x 2 ch per thread -> sP =====
        {
            const int cg = tid & 7;
            const int pp = tid >> 3;          // 0..31 pixel-pairs
            const int c0 = cg * 2;
            const int hloc = pp >> 4;         // 0/1
            const int h  = s * 2 + hloc;      // padded base row (image row-1)
            const int w0 = (pp & 15) * 2;     // even image col
            const int j0 = hloc * 32 + w0;    // local px (even)
            float sx0[2], sx1[2], sy0[2], sy1[2], id0[2], id1[2];
            #pragma unroll
            for (int ci = 0; ci < 2; ++ci) {
                const unsigned short* bp = &sSt[(c0 + ci) * 1224 + h * 36 + w0];
                float A[3], Bv[3], Cv[3], D[3];
                #pragma unroll
                for (int dr = 0; dr < 3; ++dr) {
                    const unsigned int* rp = reinterpret_cast<const unsigned int*>(bp + dr * 36);
                    const unsigned int u0 = rp[0], u1 = rp[1], u2 = rp[2];
                    A[dr]  = bf2f(u0 >> 16);        // image col w0-1
                    Bv[dr] = bf2f(u1 & 0xffffu);    // w0
                    Cv[dr] = bf2f(u1 >> 16);        // w0+1
                    D[dr]  = bf2f(u2 & 0xffffu);    // w0+2
                }
                const float csa = A[0]  + 2.f * A[1]  + A[2];
                const float csb = Bv[0] + 2.f * Bv[1] + Bv[2];
                const float csc = Cv[0] + 2.f * Cv[1] + Cv[2];
                const float csd = D[0]  + 2.f * D[1]  + D[2];
                sx0[ci] = csc - csa;
                sx1[ci] = csd - csb;
                sy0[ci] = (A[2] + 2.f * Bv[2] + Cv[2]) - (A[0] + 2.f * Bv[0] + Cv[0]);
                sy1[ci] = (Bv[2] + 2.f * Cv[2] + D[2]) - (Bv[0] + 2.f * Cv[0] + D[0]);
                id0[ci] = Bv[1];
                id1[ci] = Cv[1];
            }
            unsigned int* r0 = reinterpret_cast<unsigned int*>(&sP[j0 * 72 + c0]);
            unsigned int* r1 = reinterpret_cast<unsigned int*>(&sP[(j0 + 1) * 72 + c0]);
            r0[0]  = packbf(sx0[0], sx0[1]);
            r0[8]  = packbf(sy0[0], sy0[1]);
            r0[16] = packbf(id0[0], id0[1]);
            r1[0]  = packbf(sx1[0], sx1[1]);
            r1[8]  = packbf(sy1[0], sy1[1]);
            r1[16] = packbf(id1[0], id1[1]);
        }
        __syncthreads();

        // ===== [B] GEMM1: acc1[n] (16x16 tiles), A from sP, B regs =====
        f32x4 acc1[8];
        #pragma unroll
        for (int n = 0; n < 8; ++n) { acc1[n][0]=0.f; acc1[n][1]=0.f; acc1[n][2]=0.f; acc1[n][3]=0.f; }
        #pragma unroll
        for (int kk = 0; kk < 2; ++kk) {
            const short8v a = *reinterpret_cast<const short8v*>(&sP[(wv * 16 + lr) * 72 + kk * 32 + lg * 8]);
            #pragma unroll
            for (int n = 0; n < 8; ++n)
                acc1[n] = __builtin_amdgcn_mfma_f32_16x16x32_bf16(a, w1f[n][kk], acc1[n], 0, 0, 0);
        }
        // epilogue: bias+relu, pack 8 consecutive features/lane -> one b128 per r
        #pragma unroll
        for (int r = 0; r < 4; ++r) {
            const int row = wv * 16 + lg * 4 + r;
            unsigned int pk0, pk1, pk2, pk3;
            pk0 = packbf(fmaxf(acc1[0][r] + b1v[0], 0.f), fmaxf(acc1[1][r] + b1v[1], 0.f));
            pk1 = packbf(fmaxf(acc1[2][r] + b1v[2], 0.f), fmaxf(acc1[3][r] + b1v[3], 0.f));
            pk2 = packbf(fmaxf(acc1[4][r] + b1v[4], 0.f), fmaxf(acc1[5][r] + b1v[5], 0.f));
            pk3 = packbf(fmaxf(acc1[6][r] + b1v[6], 0.f), fmaxf(acc1[7][r] + b1v[7], 0.f));
            uint4 u; u.x = pk0; u.y = pk1; u.z = pk2; u.w = pk3;
            *reinterpret_cast<uint4*>(&sH[row * 136 + lr * 8]) = u;
        }
        __syncthreads();

        // ===== [C] GEMM2 + residual (exact f32 identity) =====
        f32x4 acc2; acc2[0]=0.f; acc2[1]=0.f; acc2[2]=0.f; acc2[3]=0.f;
        #pragma unroll
        for (int ksx = 0; ksx < 4; ++ksx) {
            const short8v a2 = *reinterpret_cast<const short8v*>(&sH[(wv * 16 + lr) * 136 + ksx * 32 + lg * 8]);
            acc2 = __builtin_amdgcn_mfma_f32_16x16x32_bf16(a2, w2f[ksx], acc2, 0, 0, 0);
        }
        const int pbase = s * 64 + wv * 16;
        const int4   mi  = *reinterpret_cast<const int4*>(&rmask[b * 1024 + pbase + lg * 4]);
        const float4 idv = *reinterpret_cast<const float4*>(&state[(size_t)b * 16384 + lr * 1024 + pbase + lg * 4]);
        float xv[4];
        xv[0] = fmaf(acc2[0] + b2v, (float)mi.x, idv.x);
        xv[1] = fmaf(acc2[1] + b2v, (float)mi.y, idv.y);
        xv[2] = fmaf(acc2[2] + b2v, (float)mi.z, idv.z);
        xv[3] = fmaf(acc2[3] + b2v, (float)mi.w, idv.w);
        if (lr == 3) {                       // new alpha -> sA
            const int p0 = pbase + lg * 4;
            const int h2 = p0 >> 5, w2c = p0 & 31;
            float* dst = &sA[(h2 + 1) * 34 + (w2c + 1)];
            dst[0] = xv[0]; dst[1] = xv[1]; dst[2] = xv[2]; dst[3] = xv[3];
        }
        __syncthreads();

        // ===== [D] gate previous strip (its sA neighborhood is now complete) =====
        if (s > 0) do_gate(pbase_prev, xp);
        xp[0] = xv[0]; xp[1] = xv[1]; xp[2] = xv[2]; xp[3] = xv[3];
        pbase_prev = pbase;
    }
    do_gate(pbase_prev, xp);   // strip 15
}

extern "C" void kernel_launch(void* const* d_in, const int* in_sizes, int n_in,
                              void* d_out, int out_size, void* d_ws, size_t ws_size,
                              hipStream_t stream) {
    const float* state = (const float*)d_in[0];
    const int*   rmask = (const int*)d_in[1];
    const float* w1    = (const float*)d_in[2];
    const float* b1    = (const float*)d_in[3];
    const float* w2    = (const float*)d_in[4];
    const float* b2    = (const float*)d_in[5];
    float* outp = (float*)d_out;

    const int B = in_sizes[0] / (16 * 32 * 32);   // 1024
    hipLaunchKernelGGL(nca_mfma, dim3(B), dim3(TPB), 0, stream,
                       state, rmask, w1, b1, w2, b2, outp);
}